// Round 5
// baseline (643.485 us; speedup 1.0000x reference)
//
#include <hip/hip_runtime.h>
#include <hip/hip_bf16.h>

#define U_CNT 200000
#define I_CNT 100000
#define N_CNT 300000
#define E_CNT 1000000
#define ATTR_D 8
#define H_DIM 32
#define NB_SCAN ((N_CNT + 255) / 256)
#define NB_E ((E_CNT + 255) / 256)          // 3907 edge blocks
#define IB 128                               // items per item-block
#define NB_I ((I_CNT + IB - 1) / IB)         // 782 item blocks
#define NB_U 512                             // user blocks (grid-stride)

// NOTE (rounds 1-4): all float inputs and the output are FLOAT32. absmax floor
// 1.95e-3 == bf16 rounding of the *reference*; threshold 1.26e-2.
// NOTE (round 5): k_edge_mlp was atomic-bound (4M atomics -> 2M int atomics).
// NOTE (round 6): deg via segment-sum post-scatter.
// NOTE (round 7): rank-capture scatter (no cursor atomics) + y-space reform
// (y = dis*x; l2norm scale-invariant). 1098 -> 951 us.
// NOTE (round 8): k_items register-blocked LDS GEMM. 951 -> 886 us.
// NOTE (round 9): bf16 y-storage. FETCH halved but only -9% -> latency-bound.
// NOTE (round 10): k_prop 4 nodes/wave, 16 lanes/node. 830 -> 634 us, matched.
// NOTE (round 11, this round): (a) k_items was LDS-PIPE bound (35 LDS-cyc per
// 16 fma; 45us chip-wide on the per-CU LDS pipe). New: bf16 LDS tiles
// (XT[128][136] + W[128][64] = 50.8KB, 3 blk/CU), 4x8 reg tile -> 20 LDS-cyc
// per 32 fma. (b) k_edge_mlp is scattered-atomic-wall bound (VALU 9%) ->
// fuse items+users (independent of dis) under it in one k_front kernel;
// x-hat stored without dis; new k_ydis folds dis after k_deg.

typedef unsigned short ubf;

__device__ __forceinline__ float b2f(ubf b) {
    return __uint_as_float((unsigned)b << 16);
}
__device__ __forceinline__ ubf f2b(float v) {
    unsigned u = __float_as_uint(v);
    u += 0x7fffu + ((u >> 16) & 1u);           // round to nearest even
    return (ubf)(u >> 16);
}
__device__ __forceinline__ unsigned pk2(float lo, float hi) {
    return (unsigned)f2b(lo) | ((unsigned)f2b(hi) << 16);
}
__device__ __forceinline__ float4 b4f(ushort4 u) {
    return make_float4(b2f(u.x), b2f(u.y), b2f(u.z), b2f(u.w));
}

// ---------------- fused front: edge MLP+hist | items x-hat | users x-hat ----------------
__global__ void __launch_bounds__(256)
k_front(const int* __restrict__ src, const int* __restrict__ dst,
        const float* __restrict__ attr,
        const float* __restrict__ W1, const float* __restrict__ b1,
        const float* __restrict__ W2, const float* __restrict__ b2,
        int2* __restrict__ wr, int* __restrict__ cnt,
        const float* __restrict__ audio, const float* __restrict__ art,
        const float* __restrict__ alb, const int* __restrict__ aid,
        const int* __restrict__ alid, const float* __restrict__ Wp,
        const float* __restrict__ bp, ubf* __restrict__ yitem,
        const float* __restrict__ user_w, ubf* __restrict__ yuser) {
    __shared__ __align__(16) ubf shm[128 * 136 + 128 * 64];   // 51.2 KB
    int t = threadIdx.x;
    int bx = blockIdx.x;

    if (bx < NB_E) {
        // ---------------- edge role ----------------
        float* ef = (float*)shm;            // [sW1 256][sb1 32][sW2 32][sb2 1]
        float* sW1 = ef;
        float* sb1 = ef + 256;
        float* sW2 = ef + 288;
        float* sb2 = ef + 320;
        sW1[t] = W1[t];
        if (t < H_DIM) { sb1[t] = b1[t]; sW2[t] = W2[t]; }
        if (t == 0) sb2[0] = b2[0];
        __syncthreads();
        int e = bx * 256 + t;
        if (e >= E_CNT) return;
        const float4* a4 = (const float4*)attr;
        float4 r0 = a4[e * 2 + 0];
        float4 r1 = a4[e * 2 + 1];
        float a[8] = {r0.x, r0.y, r0.z, r0.w, r1.x, r1.y, r1.z, r1.w};
        float z = sb2[0];
        #pragma unroll
        for (int h = 0; h < H_DIM; ++h) {
            float acc = sb1[h];
            #pragma unroll
            for (int k = 0; k < 8; ++k) acc = fmaf(a[k], sW1[k * H_DIM + h], acc);
            acc = fmaxf(acc, 0.0f);
            z = fmaf(acc, sW2[h], z);
        }
        float w = 1.0f / (1.0f + __expf(-z));
        w = fmaxf(w, 1e-6f);
        int s = src[e], d = U_CNT + dst[e];
        int rs = atomicAdd(&cnt[s], 1);
        int rd = atomicAdd(&cnt[d], 1);
        wr[e] = make_int2(__float_as_int(w), rs | (rd << 16));
    } else if (bx < NB_E + NB_I) {
        // ---------------- items role: x-hat = l2norm([audio|meta] @ Wp + bp) ----------------
        int base = (bx - NB_E) * IB;
        ubf* sXT = shm;                      // [128 f][136 item-pitch] bf16
        ubf* sW  = shm + 128 * 136;          // [128 k][64 d] bf16
        // stage Wp -> bf16 (2048 float4 = 8192 floats)
        {
            const float4* wg = (const float4*)Wp;
            #pragma unroll
            for (int r = 0; r < 8; ++r) {
                int idx = r * 256 + t;
                float4 v = wg[idx];
                ushort4 o = make_ushort4(f2b(v.x), f2b(v.y), f2b(v.z), f2b(v.w));
                *(ushort4*)&sW[idx * 4] = o;
            }
        }
        // stage audio -> sXT[f][i] transposed (128 items x 16 float4)
        {
            const float4* g = (const float4*)audio + (size_t)base * 16;
            #pragma unroll
            for (int r = 0; r < 8; ++r) {
                int idx = r * 256 + t;           // 0..2047
                int i = idx >> 4, fq = idx & 15;
                float4 v = make_float4(0.f, 0.f, 0.f, 0.f);
                if (base + i < I_CNT) v = g[idx];
                sXT[(4 * fq + 0) * 136 + i] = f2b(v.x);
                sXT[(4 * fq + 1) * 136 + i] = f2b(v.y);
                sXT[(4 * fq + 2) * 136 + i] = f2b(v.z);
                sXT[(4 * fq + 3) * 136 + i] = f2b(v.w);
            }
        }
        // stage meta -> sXT[64+f][i]
        {
            int lane = t & 63, wv = t >> 6;
            for (int i = wv; i < IB; i += 4) {
                int it = base + i;
                float v = 0.f;
                if (it < I_CNT) {
                    int a_ = aid[it], al_ = alid[it];
                    v = art[a_ * 64 + lane] + alb[al_ * 64 + lane];
                }
                sXT[(64 + lane) * 136 + i] = f2b(v);
            }
        }
        __syncthreads();
        int og = t & 7;                      // outs 8og..8og+7
        int igr = t >> 3;                    // items 4igr..4igr+3
        float c[4][8];
        {
            float bv[8];
            #pragma unroll
            for (int j = 0; j < 8; ++j) bv[j] = bp[8 * og + j];
            #pragma unroll
            for (int i = 0; i < 4; ++i)
                #pragma unroll
                for (int j = 0; j < 8; ++j) c[i][j] = bv[j];
        }
        const ubf* xcol = &sXT[4 * igr];
        const ubf* wrow = &sW[8 * og];
        #pragma unroll 2
        for (int k = 0; k < 128; ++k) {
            ushort4 xu = *(const ushort4*)&xcol[k * 136];
            uint4 wu = *(const uint4*)&wrow[k * 64];
            float x[4] = {b2f(xu.x), b2f(xu.y), b2f(xu.z), b2f(xu.w)};
            float w[8];
            w[0] = __uint_as_float(wu.x << 16); w[1] = __uint_as_float(wu.x & 0xffff0000u);
            w[2] = __uint_as_float(wu.y << 16); w[3] = __uint_as_float(wu.y & 0xffff0000u);
            w[4] = __uint_as_float(wu.z << 16); w[5] = __uint_as_float(wu.z & 0xffff0000u);
            w[6] = __uint_as_float(wu.w << 16); w[7] = __uint_as_float(wu.w & 0xffff0000u);
            #pragma unroll
            for (int i = 0; i < 4; ++i)
                #pragma unroll
                for (int j = 0; j < 8; ++j) c[i][j] = fmaf(x[i], w[j], c[i][j]);
        }
        #pragma unroll
        for (int i = 0; i < 4; ++i) {
            float ss = 0.f;
            #pragma unroll
            for (int j = 0; j < 8; ++j) ss += c[i][j] * c[i][j];
            ss += __shfl_xor(ss, 1, 64);
            ss += __shfl_xor(ss, 2, 64);
            ss += __shfl_xor(ss, 4, 64);
            int it = base + 4 * igr + i;
            if (it < I_CNT) {
                float q = 1.0f / fmaxf(sqrtf(ss), 1e-12f);
                uint4 o;
                o.x = pk2(c[i][0] * q, c[i][1] * q);
                o.y = pk2(c[i][2] * q, c[i][3] * q);
                o.z = pk2(c[i][4] * q, c[i][5] * q);
                o.w = pk2(c[i][6] * q, c[i][7] * q);
                *(uint4*)&yitem[(size_t)it * 64 + 8 * og] = o;
            }
        }
    } else {
        // ---------------- users role: x-hat = l2norm(user_w) ----------------
        int lane = t & 63;
        int wv = ((bx - NB_E - NB_I) * 256 + t) >> 6;
        const int nw = NB_U * 4;
        for (int r = wv; r < U_CNT; r += nw) {
            int idx = r * 64 + lane;
            float v = user_w[idx];
            float ss = v * v;
            #pragma unroll
            for (int m = 32; m >= 1; m >>= 1) ss += __shfl_xor(ss, m, 64);
            yuser[idx] = f2b(v / fmaxf(sqrtf(ss), 1e-12f));
        }
    }
}

// ---------------- exclusive scan of cnt -> offs (3 kernels) ----------------
__global__ void k_scan1(const int* __restrict__ cnt, int* __restrict__ incl,
                        int* __restrict__ bsums) {
    __shared__ int s[256];
    int t = threadIdx.x;
    int i = blockIdx.x * 256 + t;
    int v = (i < N_CNT) ? cnt[i] : 0;
    s[t] = v;
    __syncthreads();
    #pragma unroll
    for (int off = 1; off < 256; off <<= 1) {
        int x = (t >= off) ? s[t - off] : 0;
        __syncthreads();
        s[t] += x;
        __syncthreads();
    }
    if (i < N_CNT) incl[i] = s[t];
    if (t == 255) bsums[blockIdx.x] = s[255];
}

__global__ void k_scan2(const int* __restrict__ bsums, int* __restrict__ bbase, int nb) {
    __shared__ int s[256];
    __shared__ int carry_s;
    int t = threadIdx.x;
    if (t == 0) carry_s = 0;
    __syncthreads();
    for (int start = 0; start < nb; start += 256) {
        int i = start + t;
        int v = (i < nb) ? bsums[i] : 0;
        s[t] = v;
        __syncthreads();
        #pragma unroll
        for (int off = 1; off < 256; off <<= 1) {
            int x = (t >= off) ? s[t - off] : 0;
            __syncthreads();
            s[t] += x;
            __syncthreads();
        }
        int carry = carry_s;
        if (i < nb) bbase[i] = carry + s[t] - v;  // exclusive
        __syncthreads();
        if (t == 255) carry_s += s[255];
        __syncthreads();
    }
}

__global__ void k_scan3(const int* __restrict__ incl, const int* __restrict__ cnt,
                        const int* __restrict__ bbase, int* __restrict__ offs) {
    int i = blockIdx.x * 256 + threadIdx.x;
    if (i < N_CNT) offs[i] = bbase[blockIdx.x] + incl[i] - cnt[i];
    if (i == 0) offs[N_CNT] = 2 * E_CNT;
}

// ---------------- scatter edges into CSR at offs[node]+rank (no atomics) ----------------
__global__ void k_scatter(const int* __restrict__ src, const int* __restrict__ dst,
                          const int2* __restrict__ wr, const int* __restrict__ offs,
                          int2* __restrict__ csr) {
    int e = blockIdx.x * 256 + threadIdx.x;
    if (e >= E_CNT) return;
    int2 v = wr[e];
    unsigned rk = (unsigned)v.y;
    int s = src[e], d = U_CNT + dst[e];
    csr[offs[s] + (rk & 0xffffu)] = make_int2(d, v.x);   // row under s, partner d
    csr[offs[d] + (rk >> 16)]     = make_int2(s, v.x);   // row under d, partner s
}

// ---------------- deg via segment sum (no atomics), dis = rsqrt(1+sum) ----------------
__global__ void k_deg(const int* __restrict__ offs, const int2* __restrict__ csr,
                      float* __restrict__ dis) {
    int i = blockIdx.x * 256 + threadIdx.x;
    if (i >= N_CNT) return;
    int b = offs[i], e = offs[i + 1];
    float s = 1.0f;                      // self loop weight
    for (int k = b; k < e; ++k) s += __int_as_float(csr[k].y);
    dis[i] = rsqrtf(s);                  // s >= 1 always
}

// ---------------- y = dis (.) x-hat, in place; optionally init fp32 acc ----------------
__global__ void k_ydis(const float* __restrict__ dis, ubf* __restrict__ y,
                       float* __restrict__ acc, int use_acc) {
    const int total = N_CNT * 8;         // uint4 chunks of 8 bf16
    for (int idx = blockIdx.x * 256 + threadIdx.x; idx < total;
         idx += gridDim.x * 256) {
        float d = dis[idx >> 3];
        uint4 v = ((uint4*)y)[idx];
        float f0 = b2f((ubf)(v.x & 0xffffu)) * d, f1 = b2f((ubf)(v.x >> 16)) * d;
        float f2 = b2f((ubf)(v.y & 0xffffu)) * d, f3 = b2f((ubf)(v.y >> 16)) * d;
        float f4 = b2f((ubf)(v.z & 0xffffu)) * d, f5 = b2f((ubf)(v.z >> 16)) * d;
        float f6 = b2f((ubf)(v.w & 0xffffu)) * d, f7 = b2f((ubf)(v.w >> 16)) * d;
        uint4 o;
        o.x = pk2(f0, f1); o.y = pk2(f2, f3);
        o.z = pk2(f4, f5); o.w = pk2(f6, f7);
        ((uint4*)y)[idx] = o;
        if (use_acc) {
            ((float4*)acc)[idx * 2 + 0] = make_float4(f0, f1, f2, f3);
            ((float4*)acc)[idx * 2 + 1] = make_float4(f4, f5, f6, f7);
        }
    }
}

// ---------------- LGConv round: 4 nodes/wave, 16 lanes/node, ushort4/lane ----------------
__global__ void k_prop(const int* __restrict__ offs, const int2* __restrict__ csr,
                       const float* __restrict__ dis,
                       const ubf* __restrict__ yin, ubf* __restrict__ yout,
                       float* __restrict__ acc, int use_acc) {
    int lane = threadIdx.x & 63;
    int g = lane >> 4;                   // node group 0..3
    int s4 = (lane & 15) * 4;            // dims s4..s4+3
    int wv = (blockIdx.x * 256 + threadIdx.x) >> 6;
    int c = wv * 4 + g;
    if (c >= N_CNT) return;
    int e = offs[c], end = offs[c + 1];
    float dc = dis[c];
    float4 a0 = make_float4(0.f, 0.f, 0.f, 0.f);
    float4 a1 = a0, a2 = a0, a3 = a0;
    for (; e + 3 < end; e += 4) {
        int2 e0 = csr[e], e1 = csr[e + 1], e2 = csr[e + 2], e3 = csr[e + 3];
        ushort4 g0 = *(const ushort4*)&yin[(size_t)e0.x * 64 + s4];
        ushort4 g1 = *(const ushort4*)&yin[(size_t)e1.x * 64 + s4];
        ushort4 g2 = *(const ushort4*)&yin[(size_t)e2.x * 64 + s4];
        ushort4 g3 = *(const ushort4*)&yin[(size_t)e3.x * 64 + s4];
        float w0 = __int_as_float(e0.y), w1 = __int_as_float(e1.y);
        float w2 = __int_as_float(e2.y), w3 = __int_as_float(e3.y);
        float4 f0 = b4f(g0), f1 = b4f(g1), f2 = b4f(g2), f3 = b4f(g3);
        a0.x = fmaf(w0, f0.x, a0.x); a0.y = fmaf(w0, f0.y, a0.y);
        a0.z = fmaf(w0, f0.z, a0.z); a0.w = fmaf(w0, f0.w, a0.w);
        a1.x = fmaf(w1, f1.x, a1.x); a1.y = fmaf(w1, f1.y, a1.y);
        a1.z = fmaf(w1, f1.z, a1.z); a1.w = fmaf(w1, f1.w, a1.w);
        a2.x = fmaf(w2, f2.x, a2.x); a2.y = fmaf(w2, f2.y, a2.y);
        a2.z = fmaf(w2, f2.z, a2.z); a2.w = fmaf(w2, f2.w, a2.w);
        a3.x = fmaf(w3, f3.x, a3.x); a3.y = fmaf(w3, f3.y, a3.y);
        a3.z = fmaf(w3, f3.z, a3.z); a3.w = fmaf(w3, f3.w, a3.w);
    }
    for (; e < end; ++e) {
        int2 ee = csr[e];
        ushort4 gg = *(const ushort4*)&yin[(size_t)ee.x * 64 + s4];
        float ww = __int_as_float(ee.y);
        float4 ff = b4f(gg);
        a0.x = fmaf(ww, ff.x, a0.x); a0.y = fmaf(ww, ff.y, a0.y);
        a0.z = fmaf(ww, ff.z, a0.z); a0.w = fmaf(ww, ff.w, a0.w);
    }
    size_t idx = (size_t)c * 64 + s4;
    float4 self = b4f(*(const ushort4*)&yin[idx]);
    float dc2 = dc * dc;
    float4 r;
    r.x = dc2 * (((a0.x + a1.x) + (a2.x + a3.x)) + self.x);
    r.y = dc2 * (((a0.y + a1.y) + (a2.y + a3.y)) + self.y);
    r.z = dc2 * (((a0.z + a1.z) + (a2.z + a3.z)) + self.z);
    r.w = dc2 * (((a0.w + a1.w) + (a2.w + a3.w)) + self.w);
    *(ushort4*)&yout[idx] = make_ushort4(f2b(r.x), f2b(r.y), f2b(r.z), f2b(r.w));
    if (use_acc) {
        float4* ap = (float4*)&acc[idx];
        float4 av = *ap;
        av.x += r.x; av.y += r.y; av.z += r.z; av.w += r.w;
        *ap = av;
    }
}

// ---------------- epilogue A: l2norm(acc)  (acc fp32, may alias out) ----------------
__global__ void k_final_acc(const float* __restrict__ acc, float* __restrict__ out) {
    int lane = threadIdx.x & 63;
    int c = (blockIdx.x * 256 + threadIdx.x) >> 6;
    if (c >= N_CNT) return;
    int idx = c * 64 + lane;
    float v = acc[idx];
    float ss = v * v;
    #pragma unroll
    for (int m = 32; m >= 1; m >>= 1) ss += __shfl_xor(ss, m, 64);
    out[idx] = v / fmaxf(sqrtf(ss), 1e-12f);
}

// ---------------- epilogue B: l2norm(y0+y1+y2+y3), all bf16 ----------------
__global__ void k_final_sum(const ubf* __restrict__ y0, const ubf* __restrict__ y1,
                            const ubf* __restrict__ y2, const ubf* __restrict__ y3,
                            float* __restrict__ out) {
    int lane = threadIdx.x & 63;
    int c = (blockIdx.x * 256 + threadIdx.x) >> 6;
    if (c >= N_CNT) return;
    int idx = c * 64 + lane;
    float v = b2f(y0[idx]) + b2f(y1[idx]) + b2f(y2[idx]) + b2f(y3[idx]);
    float ss = v * v;
    #pragma unroll
    for (int m = 32; m >= 1; m >>= 1) ss += __shfl_xor(ss, m, 64);
    out[idx] = v / fmaxf(sqrtf(ss), 1e-12f);
}

extern "C" void kernel_launch(void* const* d_in, const int* in_sizes, int n_in,
                              void* d_out, int out_size, void* d_ws, size_t ws_size,
                              hipStream_t stream) {
    const int*   edge_src   = (const int*)  d_in[0];
    const int*   edge_dst   = (const int*)  d_in[1];
    const float* edge_attr  = (const float*)d_in[2];
    const float* user_w     = (const float*)d_in[3];
    const float* artist_w   = (const float*)d_in[4];
    const float* album_w    = (const float*)d_in[5];
    const float* item_audio = (const float*)d_in[6];
    const int*   artist_ids = (const int*)  d_in[7];
    const int*   album_ids  = (const int*)  d_in[8];
    const float* Wp         = (const float*)d_in[9];
    const float* bp         = (const float*)d_in[10];
    const float* W1         = (const float*)d_in[11];
    const float* b1         = (const float*)d_in[12];
    const float* W2         = (const float*)d_in[13];
    const float* b2         = (const float*)d_in[14];

    char* p = (char*)d_ws;
    auto carve = [&](size_t bytes) -> void* {
        void* q = (void*)p;
        p += (bytes + 255) & ~(size_t)255;
        return q;
    };
    // common carve (~28 MB)
    float* dis    = (float*)carve((size_t)N_CNT * 4);
    int2*  wr     = (int2*) carve((size_t)E_CNT * 8);       // {w, rank_s|rank_d<<16}
    int*   cnt    = (int*)  carve((size_t)N_CNT * 4);
    int*   offs   = (int*)  carve((size_t)(N_CNT + 1) * 4);
    int*   incl   = (int*)  carve((size_t)N_CNT * 4);
    int*   bsums  = (int*)  carve((size_t)NB_SCAN * 4);
    int*   bbase  = (int*)  carve((size_t)NB_SCAN * 4);
    int2*  csr    = (int2*) carve((size_t)2 * E_CNT * 8);
    const size_t YB = (size_t)N_CNT * 64 * 2;      // 38.4 MB per bf16 y buffer
    size_t used = (size_t)(p - (char*)d_ws);
    // Path B (no acc RMW) needs y0..y3 bf16 in ws; else ping-pong + fp32 acc in d_out.
    int no_acc = (ws_size >= used + 4 * YB + (size_t)4096) ? 1 : 0;
    ubf *y0, *y1, *y2, *y3;
    float* acc = nullptr;
    if (no_acc) {
        y0 = (ubf*)carve(YB);
        y1 = (ubf*)carve(YB);
        y2 = (ubf*)carve(YB);
        y3 = (ubf*)carve(YB);
    } else {
        y0 = (ubf*)carve(YB);
        y1 = (ubf*)carve(YB);
        y2 = y0;
        y3 = y1;
        acc = (float*)d_out;           // fp32 accumulator lives in d_out
    }
    (void)in_sizes; (void)n_in; (void)out_size;

    hipMemsetAsync(cnt, 0, (size_t)N_CNT * 4, stream);
    // fused: edge MLP+hist (request-wall) overlapped with items/users x-hat
    k_front<<<NB_E + NB_I + NB_U, 256, 0, stream>>>(
        edge_src, edge_dst, edge_attr, W1, b1, W2, b2, wr, cnt,
        item_audio, artist_w, album_w, artist_ids, album_ids, Wp, bp,
        y0 + (size_t)U_CNT * 64, user_w, y0);
    k_scan1  <<<NB_SCAN, 256, 0, stream>>>(cnt, incl, bsums);
    k_scan2  <<<1, 256, 0, stream>>>(bsums, bbase, NB_SCAN);
    k_scan3  <<<NB_SCAN, 256, 0, stream>>>(incl, cnt, bbase, offs);
    k_scatter<<<NB_E, 256, 0, stream>>>(edge_src, edge_dst, wr, offs, csr);
    k_deg    <<<NB_SCAN, 256, 0, stream>>>(offs, csr, dis);
    k_ydis   <<<2048, 256, 0, stream>>>(dis, y0, acc, no_acc ? 0 : 1);
    // 4 nodes per wave -> N/4 waves -> N/16 blocks of 256
    const int PROP_BLKS = N_CNT / 16;    // 18750
    if (no_acc) {
        k_prop<<<PROP_BLKS, 256, 0, stream>>>(offs, csr, dis, y0, y1, nullptr, 0);
        k_prop<<<PROP_BLKS, 256, 0, stream>>>(offs, csr, dis, y1, y2, nullptr, 0);
        k_prop<<<PROP_BLKS, 256, 0, stream>>>(offs, csr, dis, y2, y3, nullptr, 0);
        k_final_sum<<<N_CNT / 4, 256, 0, stream>>>(y0, y1, y2, y3, (float*)d_out);
    } else {
        // y0 -> y1 -> y0 -> y1 (bf16), accumulating fp32 into acc (= d_out)
        k_prop<<<PROP_BLKS, 256, 0, stream>>>(offs, csr, dis, y0, y1, acc, 1);
        k_prop<<<PROP_BLKS, 256, 0, stream>>>(offs, csr, dis, y1, y0, acc, 1);
        k_prop<<<PROP_BLKS, 256, 0, stream>>>(offs, csr, dis, y0, y1, acc, 1);
        k_final_acc<<<N_CNT / 4, 256, 0, stream>>>(acc, (float*)d_out);
    }
}